// Round 11
// baseline (35.186 us; speedup 1.0000x reference)
//
#include <hip/hip_runtime.h>
#include <hip/hip_bf16.h>

typedef __attribute__((ext_vector_type(8))) short short8v;
typedef __attribute__((ext_vector_type(4))) float float4v;

// Problem constants
#define NB 64
#define NN 2048
#define ED 128
#define GRID_P 512            // 4 chunks of 64 pairs per block

static __device__ __forceinline__ unsigned int packbf2(float a, float b) {
    __hip_bfloat162 h = __float22bfloat162_rn(make_float2(a, b));
    return *(unsigned int*)&h;
}

// ---------------- Single fused kernel ----------------
// NOTE: no min-waves launch-bounds arg — a VGPR cap silently kills register prefetch (r4/r8/r9 lesson).
__global__ __launch_bounds__(256) void k_fused(
    const float* __restrict__ users, const int* __restrict__ uids,
    const float* __restrict__ top_user, const float* __restrict__ question,
    const float* __restrict__ W1, const float* __restrict__ b1,
    const float* __restrict__ W2, const float* __restrict__ b2,
    const float* __restrict__ W3, const float* __restrict__ b3,
    const float* __restrict__ fw1, const float* __restrict__ fb1,
    const float* __restrict__ fw2, const float* __restrict__ fb2,
    const float* __restrict__ fw3, const float* __restrict__ fb3,
    float* __restrict__ out)
{
    __shared__ __align__(16) unsigned int X2[2][64][132];   // 2 x 33792 B
    __shared__ float pscore[2][2][64];                      // [slot][nhalf][pair]
    __shared__ float qs[132], tus[132];
    __shared__ float w3s[192];
    __shared__ __align__(16) __hip_bfloat16 ext2[320];  // [0(64)|W3r0(64)|0(64)|W3r2(64)|0(64)]
    __shared__ float c1q[128], qtl[64], weffl[64];
    __shared__ float D4f[256];
    __shared__ float gsh[16];
    __shared__ float sh_beff, sh_shigh;

    const int tid = threadIdx.x;
    const int w = tid >> 6, lane = tid & 63;
    const int bid = blockIdx.x;
    const int b = bid >> 3;            // 8 blocks per batch
    const int cg = bid & 7;
    const int base = b*NN + cg*256;

    // prefix property: uids nonzero exactly for n < length (monotone chunk activity)
    if (uids[base] == 0) return;
    const bool a1 = (uids[base +  64] != 0);
    const bool a2 = (uids[base + 128] != 0);
    const bool a3 = (uids[base + 192] != 0);

    const int gfr = lane >> 4, li = lane & 15;
    const int nhalf = w >> 1;            // tap half
    const int mbase = (w & 1) * 32;      // pair half
    const int h = lane >> 5, j = lane & 31;
    const int r0 = w * 16;

    const int m0 = (w == 0) ? uids[base + lane] : 1;
    const int m1 = (w == 0) ? uids[base +  64 + lane] : 1;
    const int m2 = (w == 0) ? uids[base + 128 + lane] : 1;
    const int m3 = (w == 0) ? uids[base + 192 + lane] : 1;

    const float w10=W1[0], w11=W1[1], w12=W1[2];
    const float w20=W2[0], w21=W2[1], w22=W2[2];
    const float w23=W2[3], w24=W2[4], w25=W2[5];
    const float b1v=b1[0], b2v=b2[0], b3v=b3[0];

    // ---- issue users loads for chunks 0,1 immediately (latency hides under stages A/B) ----
    float4 bufA[8], bufB[8];
    #pragma unroll
    for (int pass = 0; pass < 8; ++pass) {
        const int r = r0 + pass*2 + h;
        bufA[pass] = *(const float4*)(users + (size_t)(base + r)*ED + 4*j);
        bufB[pass] = *(const float4*)(users + (size_t)(base + 64 + r)*ED + 4*j);
    }

    // ---- stage A: wave-role LDS staging (overlapped with users loads in flight) ----
    if (w == 0) {
        float2 qv = ((const float2*)(question + b*ED))[lane];
        ((float2*)qs)[lane] = qv;
        if (lane == 63) { qs[128]=0.f; qs[129]=0.f; qs[130]=0.f; qs[131]=0.f; }
        const float nx = __shfl(qv.x, (lane+1)&63, 64);
        const float ny = __shfl(qv.y, (lane+1)&63, 64);
        float ca = fmaxf(b1v + w10*qv.x + w11*qv.y + w12*nx, 0.f);
        float cb = fmaxf(b1v + w10*qv.y + w11*nx   + w12*ny, 0.f);
        if (lane == 63) { ca = 0.f; cb = 0.f; }    // conv pads (elems 126,127)
        c1q[2*lane] = ca; c1q[2*lane+1] = cb;
    } else if (w == 1) {
        float2 tv = ((const float2*)(top_user + b*ED))[lane];
        ((float2*)tus)[lane] = tv;
        if (lane == 63) { tus[128]=0.f; tus[129]=0.f; tus[130]=0.f; tus[131]=0.f; }
    } else if (w == 2) {
        w3s[lane] = W3[lane];
        w3s[64+lane] = W3[64+lane];
        w3s[128+lane] = W3[128+lane];
        if (lane < 16) {
            float s = 0.f;
            #pragma unroll
            for (int i = 0; i < 16; ++i) s += fw3[i] * fw2[i*16 + lane];
            gsh[lane] = s;
        }
    } else {
        #pragma unroll
        for (int k5 = 0; k5 < 5; ++k5) {
            const int idx = k5*64 + lane;
            float v = 0.f;
            if (idx >= 64 && idx < 128) v = W3[idx-64];               // row 0
            else if (idx >= 192 && idx < 256) v = W3[128 + idx-192];  // row 2
            ext2[idx] = __float2bfloat16(v);
        }
    }
    __syncthreads();   // sync A

    // ---- stage B: per-lane consts + B-fragment gather + role work ----
    const float q0=qs[4*j], q1=qs[4*j+1], q2=qs[4*j+2], q3=qs[4*j+3], q4=qs[4*j+4], q5=qs[4*j+5];
    float4 qp4;
    qp4.x = w23*q0 + w24*q1 + w25*q2;
    qp4.y = w23*q1 + w24*q2 + w25*q3;
    qp4.z = w23*q2 + w24*q3 + w25*q4;
    qp4.w = w23*q3 + w24*q4 + w25*q5;

    const int t0 = nhalf*32 + li, t1 = t0 + 16;
    short8v bfr0[8], bfr1[8];
    {
        const short* e2 = (const short*)ext2;
        const int off0 = 64 + gfr*8 - t0;      // min 17; bfr1 uses off0-16 >= 1
        #pragma unroll
        for (int kt = 0; kt < 8; ++kt) {
            short8v v0, v1;
            #pragma unroll
            for (int idx = 0; idx < 8; ++idx) {
                v0[idx] = e2[off0      + kt*32 + idx];
                v1[idx] = e2[off0 - 16 + kt*32 + idx];
            }
            bfr0[kt] = v0; bfr1[kt] = v1;
        }
    }

    if (w == 0) {
        float qtv = b3v;                       // b3 folded
        #pragma unroll
        for (int jj = 0; jj < 64; ++jj) qtv += w3s[64+jj] * c1q[lane+jj];
        qtl[lane] = qtv;
    } else if (w == 1) {
        const int i = 2*lane;
        const float qpa = w23*qs[i]   + w24*qs[i+1] + w25*qs[i+2];
        const float qpb = w23*qs[i+1] + w24*qs[i+2] + w25*qs[i+3];
        float c1ta = fmaxf(b1v + w10*tus[i]   + w11*tus[i+1] + w12*tus[i+2], 0.f);
        float c1tb = fmaxf(b1v + w10*tus[i+1] + w11*tus[i+2] + w12*tus[i+3], 0.f);
        float c2a  = fmaxf(b2v + w20*tus[i]   + w21*tus[i+1] + w22*tus[i+2] + qpa, 0.f);
        float c2b  = fmaxf(b2v + w20*tus[i+1] + w21*tus[i+2] + w22*tus[i+3] + qpb, 0.f);
        if (lane == 63) { c1ta=0.f; c1tb=0.f; c2a=0.f; c2b=0.f; }
        ((float4*)D4f)[lane] = make_float4(c1ta, c2a, c1tb, c2b);
    } else if (w == 2) {
        float wv = 0.f;
        if (lane < 63) {
            #pragma unroll
            for (int k = 0; k < 16; ++k) wv += gsh[k] * fw1[k*63 + lane];
        }
        weffl[lane] = wv;                      // weffl[63] = 0 masks pad tap
    } else {
        if (lane < 16) {
            float p = fw3[lane]*fb2[lane] + gsh[lane]*fb1[lane];
            p += __shfl_xor(p, 1, 64);
            p += __shfl_xor(p, 2, 64);
            p += __shfl_xor(p, 4, 64);
            p += __shfl_xor(p, 8, 64);
            if (lane == 0) sh_beff = p + fb3[0];
        }
    }
    __syncthreads();   // sync B

    const float wf0 = weffl[t0], wf1 = weffl[t1];
    const float qt0 = qtl[t0],  qt1 = qtl[t1];
    const float beff = sh_beff;

    auto prep = [&](const float4* ur, int xb) {
        #pragma unroll
        for (int pass = 0; pass < 8; ++pass) {
            const int r = r0 + pass*2 + h;
            const float4 uu = ur[pass];
            const float nx = __shfl(uu.x, (lane + 1) & 63, 64);
            const float ny = __shfl(uu.y, (lane + 1) & 63, 64);
            float c10 = fmaxf(b1v + w10*uu.x + w11*uu.y + w12*uu.z, 0.f);
            float c11 = fmaxf(b1v + w10*uu.y + w11*uu.z + w12*uu.w, 0.f);
            float c12 = fmaxf(b1v + w10*uu.z + w11*uu.w + w12*nx  , 0.f);
            float c13 = fmaxf(b1v + w10*uu.w + w11*nx   + w12*ny  , 0.f);
            float c20 = fmaxf(b2v + w20*uu.x + w21*uu.y + w22*uu.z + qp4.x, 0.f);
            float c21 = fmaxf(b2v + w20*uu.y + w21*uu.z + w22*uu.w + qp4.y, 0.f);
            float c22 = fmaxf(b2v + w20*uu.z + w21*uu.w + w22*nx   + qp4.z, 0.f);
            float c23 = fmaxf(b2v + w20*uu.w + w21*nx   + w22*ny   + qp4.w, 0.f);
            if (j == 31) { c12 = 0.f; c13 = 0.f; c22 = 0.f; c23 = 0.f; }   // conv pads
            uint2 v1; v1.x = packbf2(c10, c11); v1.y = packbf2(c12, c13);
            uint2 v2; v2.x = packbf2(c20, c21); v2.y = packbf2(c22, c23);
            *(uint2*)&X2[xb][r][2*j]      = v1;
            *(uint2*)&X2[xb][r][64 + 2*j] = v2;
        }
    };

    auto gemm = [&](int xb, int psl) {
        float4v acc00 = {0.f,0.f,0.f,0.f}, acc01 = {0.f,0.f,0.f,0.f};
        float4v acc10 = {0.f,0.f,0.f,0.f}, acc11 = {0.f,0.f,0.f,0.f};
        const char* Xb = (const char*)&X2[xb][0][0];
        #pragma unroll
        for (int kt = 0; kt < 8; ++kt) {
            const short8v aa0 = *(const short8v*)(Xb + (mbase + li)*528      + kt*64 + gfr*16);
            const short8v aa1 = *(const short8v*)(Xb + (mbase + 16 + li)*528 + kt*64 + gfr*16);
            acc00 = __builtin_amdgcn_mfma_f32_16x16x32_bf16(aa0, bfr0[kt], acc00, 0, 0, 0);
            acc01 = __builtin_amdgcn_mfma_f32_16x16x32_bf16(aa0, bfr1[kt], acc01, 0, 0, 0);
            acc10 = __builtin_amdgcn_mfma_f32_16x16x32_bf16(aa1, bfr0[kt], acc10, 0, 0, 0);
            acc11 = __builtin_amdgcn_mfma_f32_16x16x32_bf16(aa1, bfr1[kt], acc11, 0, 0, 0);
        }
        #pragma unroll
        for (int mi = 0; mi < 2; ++mi) {
            #pragma unroll
            for (int reg = 0; reg < 4; ++reg) {
                const float a0v = mi ? acc10[reg] : acc00[reg];
                const float a1v = mi ? acc11[reg] : acc01[reg];
                float v = wf0 * fmaxf(a0v + qt0, 0.f) + wf1 * fmaxf(a1v + qt1, 0.f);
                v += __shfl_xor(v, 1, 64);
                v += __shfl_xor(v, 2, 64);
                v += __shfl_xor(v, 4, 64);
                v += __shfl_xor(v, 8, 64);
                if (li == 0) pscore[psl][nhalf][mbase + mi*16 + gfr*4 + reg] = v;
            }
        }
    };

    float val = 0.f;
    auto sig = [&](int psl, int m) {
        if (w == 0) {
            const float d = pscore[psl][0][lane] + pscore[psl][1][lane] + beff - sh_shigh;
            if (m != 0) val += 1.f / (1.f + __expf(-d));
        }
    };

    // ---- stage C: prep chunk 0 ----
    prep(bufA, 0);
    __syncthreads();                       // X0 ready

    // phase 0: gemm(c0) || prep(c1) || load(c2) || shigh (w3)
    if (a2) {
        #pragma unroll
        for (int pass = 0; pass < 8; ++pass) {
            const int r = r0 + pass*2 + h;
            bufA[pass] = *(const float4*)(users + (size_t)(base + 128 + r)*ED + 4*j);
        }
    }
    gemm(0, 0);
    if (a1) prep(bufB, 1);
    if (w == 3) {
        float acc0 = qtl[lane], acc1 = 0.f;    // qtl = qterm + b3
        const float2* D2 = (const float2*)D4f;
        #pragma unroll
        for (int jj = 0; jj < 64; ++jj) {
            const float2 d = D2[lane + jj];
            acc0 = fmaf(w3s[jj],       d.x, acc0);
            acc1 = fmaf(w3s[128 + jj], d.y, acc1);
        }
        float v = weffl[lane] * fmaxf(acc0 + acc1, 0.f);
        #pragma unroll
        for (int off = 32; off > 0; off >>= 1) v += __shfl_xor(v, off, 64);
        if (lane == 0) sh_shigh = v + sh_beff;
    }
    __syncthreads();                       // pscore0(c0), X1, shigh ready

    sig(0, m0);
    if (a1) {
        // phase 1
        if (a3) {
            #pragma unroll
            for (int pass = 0; pass < 8; ++pass) {
                const int r = r0 + pass*2 + h;
                bufB[pass] = *(const float4*)(users + (size_t)(base + 192 + r)*ED + 4*j);
            }
        }
        gemm(1, 1);
        if (a2) prep(bufA, 0);
        __syncthreads();                   // pscore1(c1), X0(c2) ready

        sig(1, m1);
        if (a2) {
            // phase 2
            gemm(0, 0);
            if (a3) prep(bufB, 1);
            __syncthreads();               // pscore0(c2), X1(c3) ready

            sig(0, m2);
            if (a3) {
                // phase 3
                gemm(1, 1);
                __syncthreads();           // pscore1(c3) ready
                sig(1, m3);
            }
        }
    }

    if (w == 0) {
        #pragma unroll
        for (int off = 32; off > 0; off >>= 1) val += __shfl_xor(val, off, 64);
        if (lane == 0) atomicAdd(out, val);   // device-scope
    }
}

extern "C" void kernel_launch(void* const* d_in, const int* in_sizes, int n_in,
                              void* d_out, int out_size, void* d_ws, size_t ws_size,
                              hipStream_t stream)
{
    const float* users    = (const float*)d_in[0];
    const float* top_user = (const float*)d_in[1];
    const float* question = (const float*)d_in[2];
    const int*   uids     = (const int*)d_in[3];
    const float* W1  = (const float*)d_in[4];
    const float* b1  = (const float*)d_in[5];
    const float* W2  = (const float*)d_in[6];
    const float* b2  = (const float*)d_in[7];
    const float* W3  = (const float*)d_in[8];
    const float* b3  = (const float*)d_in[9];
    const float* fw1 = (const float*)d_in[10];
    const float* fb1 = (const float*)d_in[11];
    const float* fw2 = (const float*)d_in[12];
    const float* fb2 = (const float*)d_in[13];
    const float* fw3 = (const float*)d_in[14];
    const float* fb3 = (const float*)d_in[15];
    float* out = (float*)d_out;

    hipMemsetAsync(out, 0, sizeof(float), stream);   // graph-capturable
    hipLaunchKernelGGL(k_fused, dim3(GRID_P), dim3(256), 0, stream,
                       users, uids, top_user, question,
                       W1, b1, W2, b2, W3, b3,
                       fw1, fb1, fw2, fb2, fw3, fb3, out);
}

// Round 12
// 30.939 us; speedup vs baseline: 1.1373x; 1.1373x over previous
//
#include <hip/hip_runtime.h>
#include <hip/hip_bf16.h>

typedef __attribute__((ext_vector_type(8))) short short8v;
typedef __attribute__((ext_vector_type(4))) float float4v;

// Problem constants
#define NB 64
#define NN 2048
#define ED 128
#define GRID_P 512            // k_pairs blocks, 4 chunks of 64 pairs each

// workspace layout (float offsets)
#define WS_WEFF  0                  // 64 (weff[63], [63]=0)
#define WS_BEFF  64                 // 1
#define WS_SHIGH 128                // 64
#define WS_QTERM 192                // 64*64  (qterm + b3 folded)
#define WS_QPRE  (192+4096)         // 64*128
#define WS_BPACK (192+4096+8192)    // bf16[16384] = 4096 floats, 16B aligned

static __device__ __forceinline__ unsigned int packbf2(float a, float b) {
    __hip_bfloat162 h = __float22bfloat162_rn(make_float2(a, b));
    return *(unsigned int*)&h;
}

// ---------------- Kernel P (unchanged from r10) ----------------
__global__ __launch_bounds__(64) void k_prep(
    const float* __restrict__ top_user, const float* __restrict__ question,
    const float* __restrict__ W1, const float* __restrict__ b1,
    const float* __restrict__ W2, const float* __restrict__ b2,
    const float* __restrict__ W3, const float* __restrict__ b3,
    const float* __restrict__ fw1, const float* __restrict__ fb1,
    const float* __restrict__ fw2, const float* __restrict__ fb2,
    const float* __restrict__ fw3, const float* __restrict__ fb3,
    float* __restrict__ ws, float* __restrict__ out)
{
    const int lane = threadIdx.x;
    const int blk = blockIdx.x;
    __shared__ float g[16];
    __shared__ float w3s[192];
    w3s[lane] = W3[lane];
    w3s[64 + lane] = W3[64 + lane];
    w3s[128 + lane] = W3[128 + lane];
    if (lane < 16) {
        float s = 0.f;
        #pragma unroll
        for (int i = 0; i < 16; ++i) s += fw3[i] * fw2[i*16 + lane];
        g[lane] = s;
    }
    __syncthreads();

    if (blk >= NB) {
        const int kt = blk - NB;
        if (kt == 0) {
            if (lane == 0) out[0] = 0.f;
            float wv = 0.f;
            if (lane < 63) {
                #pragma unroll
                for (int k = 0; k < 16; ++k) wv += g[k] * fw1[k*63 + lane];
            }
            ws[WS_WEFF + lane] = wv;
            if (lane == 0) {
                float be = fb3[0];
                #pragma unroll
                for (int i = 0; i < 16; ++i) be += fw3[i] * fb2[i];
                #pragma unroll
                for (int k = 0; k < 16; ++k) be += g[k] * fb1[k];
                ws[WS_BEFF] = be;
            }
        }
        __hip_bfloat16* bp = (__hip_bfloat16*)(ws + WS_BPACK);
        const int g8 = (lane >> 4) * 8, li = lane & 15;
        #pragma unroll
        for (int nt = 0; nt < 4; ++nt) {
            const int tt = nt*16 + li;
            #pragma unroll
            for (int idx = 0; idx < 8; ++idx) {
                const int k = kt*32 + g8 + idx;
                const int j = k - tt;
                const int k2 = k - 128, j2 = k2 - tt;
                const bool v0 = (tt < 63) && (k < 126) && (j >= 0) && (j < 64);
                const bool v2 = (tt < 63) && (k2 >= 0) && (k2 < 126) && (j2 >= 0) && (j2 < 64);
                float v = (v0 ? w3s[j & 63] : 0.f) + (v2 ? w3s[128 + (j2 & 63)] : 0.f);
                bp[((kt*4 + nt)*64 + lane)*8 + idx] = __float2bfloat16(v);
            }
        }
        return;
    }

    float wv = 0.f;
    if (lane < 63) {
        #pragma unroll
        for (int k = 0; k < 16; ++k) wv += g[k] * fw1[k*63 + lane];
    }
    float be = fb3[0];
    #pragma unroll
    for (int i = 0; i < 16; ++i) be += fw3[i] * fb2[i];
    #pragma unroll
    for (int k = 0; k < 16; ++k) be += g[k] * fb1[k];

    __shared__ float q[132], tu[132], c1q[128], qt[64];
    __shared__ float4 D4[64];
    const int b = blk;
    ((float2*)q)[lane]  = ((const float2*)(question + b*ED))[lane];
    ((float2*)tu)[lane] = ((const float2*)(top_user + b*ED))[lane];
    if (lane == 63) {
        q[128]=0.f; q[129]=0.f; q[130]=0.f; q[131]=0.f;
        tu[128]=0.f; tu[129]=0.f; tu[130]=0.f; tu[131]=0.f;
    }
    __syncthreads();
    const float w10=W1[0], w11=W1[1], w12=W1[2];
    const float w20=W2[0], w21=W2[1], w22=W2[2];
    const float w23=W2[3], w24=W2[4], w25=W2[5];
    const float b1v=b1[0], b2v=b2[0], b3v=b3[0];
    const int i = 2*lane;
    float c1qa = fmaxf(b1v + w10*q[i]   + w11*q[i+1] + w12*q[i+2], 0.f);
    float c1qb = fmaxf(b1v + w10*q[i+1] + w11*q[i+2] + w12*q[i+3], 0.f);
    float qpa  = w23*q[i]   + w24*q[i+1] + w25*q[i+2];
    float qpb  = w23*q[i+1] + w24*q[i+2] + w25*q[i+3];
    float c1ta = fmaxf(b1v + w10*tu[i]   + w11*tu[i+1] + w12*tu[i+2], 0.f);
    float c1tb = fmaxf(b1v + w10*tu[i+1] + w11*tu[i+2] + w12*tu[i+3], 0.f);
    float c2a  = fmaxf(b2v + w20*tu[i]   + w21*tu[i+1] + w22*tu[i+2] + qpa, 0.f);
    float c2b  = fmaxf(b2v + w20*tu[i+1] + w21*tu[i+2] + w22*tu[i+3] + qpb, 0.f);
    if (lane == 63) { c1qa=0.f; c1qb=0.f; qpa=0.f; qpb=0.f; c1ta=0.f; c1tb=0.f; c2a=0.f; c2b=0.f; }
    c1q[i] = c1qa; c1q[i+1] = c1qb;
    ws[WS_QPRE + b*128 + i]     = qpa;
    ws[WS_QPRE + b*128 + i + 1] = qpb;
    D4[lane] = make_float4(c1ta, c2a, c1tb, c2b);
    __syncthreads();
    float qtv = 0.f;
    if (lane < 63) {
        #pragma unroll
        for (int j = 0; j < 64; ++j) qtv += w3s[64 + j] * c1q[lane + j];
    }
    qt[lane] = qtv;
    ws[WS_QTERM + b*64 + lane] = qtv + b3v;
    __syncthreads();
    float acc0 = b3v + qt[lane];
    float acc1 = 0.f;
    const float2* D2 = (const float2*)D4;
    #pragma unroll
    for (int j = 0; j < 64; ++j) {
        const float2 d = D2[lane + j];
        acc0 = fmaf(w3s[j],       d.x, acc0);
        acc1 = fmaf(w3s[128 + j], d.y, acc1);
    }
    float v = wv * fmaxf(acc0 + acc1, 0.f);
    #pragma unroll
    for (int off = 32; off > 0; off >>= 1) v += __shfl_xor(v, off, 64);
    if (lane == 0) ws[WS_SHIGH + b] = v + be;
}

// ---------------- Kernel C: 4 chunks/block, double-buffered X, prep||gemm pipeline ----------------
// NOTE: no min-waves launch-bounds arg (VGPR cap kills prefetch — r4/r8/r9).
// NOTE: prepA/prepB capture their buffer DIRECTLY (no pointer param) so bufA/bufB stay in
//       registers — a pointer-param lambda memory-homes the array (rule #20) -> scratch traffic.
__global__ __launch_bounds__(256) void k_pairs(
    const float* __restrict__ users, const int* __restrict__ uids,
    float* __restrict__ ws, float* __restrict__ out,
    const float* __restrict__ W1, const float* __restrict__ b1,
    const float* __restrict__ W2, const float* __restrict__ b2)
{
    __shared__ __align__(16) unsigned int X2[2][64][132];   // 2 x 33792 B
    __shared__ float pscore[2][2][64];                      // [slot][nhalf][pair]
    const int tid = threadIdx.x;
    const int w = tid >> 6, lane = tid & 63;
    const int bid = blockIdx.x;
    const int b = bid >> 3;            // 8 blocks per batch
    const int cg = bid & 7;
    const int base = b*NN + cg*256;

    const int g = lane >> 4, li = lane & 15;
    const int nhalf = w >> 1;            // tap half
    const int mbase = (w & 1) * 32;      // pair half
    const int h = lane >> 5, j = lane & 31;
    const int r0 = w * 16;

    // ---- issue chunk-0 users loads + B fragments BEFORE the activity gate ----
    // (rows always in-bounds; overlaps the gate's uids load latency)
    float4 bufA[8], bufB[8];
    #pragma unroll
    for (int pass = 0; pass < 8; ++pass) {
        const int r = r0 + pass*2 + h;
        bufA[pass] = *(const float4*)(users + (size_t)(base + r)*ED + 4*j);
    }
    const __hip_bfloat16* bp = (const __hip_bfloat16*)(ws + WS_BPACK);
    short8v bfr0[8], bfr1[8];
    #pragma unroll
    for (int kt = 0; kt < 8; ++kt) {
        bfr0[kt] = *(const short8v*)(bp + (((kt*4 + nhalf*2 + 0)*64 + lane) << 3));
        bfr1[kt] = *(const short8v*)(bp + (((kt*4 + nhalf*2 + 1)*64 + lane) << 3));
    }

    // prefix property: uids nonzero exactly for n < length (monotone chunk activity)
    if (uids[base] == 0) return;
    const bool a1 = (uids[base +  64] != 0);
    const bool a2 = (uids[base + 128] != 0);
    const bool a3 = (uids[base + 192] != 0);

    const int m0 = (w == 0) ? uids[base + lane] : 1;
    const int m1 = (w == 0) ? uids[base +  64 + lane] : 1;
    const int m2 = (w == 0) ? uids[base + 128 + lane] : 1;
    const int m3 = (w == 0) ? uids[base + 192 + lane] : 1;

    #pragma unroll
    for (int pass = 0; pass < 8; ++pass) {
        const int r = r0 + pass*2 + h;
        bufB[pass] = *(const float4*)(users + (size_t)(base + 64 + r)*ED + 4*j);
    }

    const float w10=W1[0], w11=W1[1], w12=W1[2];
    const float w20=W2[0], w21=W2[1], w22=W2[2];
    const float b1v=b1[0], b2v=b2[0];

    const int t0 = nhalf*32 + li, t1 = t0 + 16;
    const float wf0 = ws[WS_WEFF + t0], wf1 = ws[WS_WEFF + t1];
    const float qt0 = ws[WS_QTERM + b*64 + t0], qt1 = ws[WS_QTERM + b*64 + t1];
    const float shigh = ws[WS_SHIGH + b], beff = ws[WS_BEFF];
    const float4 qp4 = *(const float4*)&ws[WS_QPRE + b*128 + 4*j];

    // X-prep bodies: direct capture of the named buffer (keeps it in VGPRs)
#define PREP_BODY(BUF, XB)                                                          \
    {                                                                               \
        _Pragma("unroll")                                                           \
        for (int pass = 0; pass < 8; ++pass) {                                      \
            const int r = r0 + pass*2 + h;                                          \
            const float4 uu = BUF[pass];                                            \
            const float nx = __shfl(uu.x, (lane + 1) & 63, 64);                     \
            const float ny = __shfl(uu.y, (lane + 1) & 63, 64);                     \
            float c10 = fmaxf(b1v + w10*uu.x + w11*uu.y + w12*uu.z, 0.f);           \
            float c11 = fmaxf(b1v + w10*uu.y + w11*uu.z + w12*uu.w, 0.f);           \
            float c12 = fmaxf(b1v + w10*uu.z + w11*uu.w + w12*nx  , 0.f);           \
            float c13 = fmaxf(b1v + w10*uu.w + w11*nx   + w12*ny  , 0.f);           \
            float c20 = fmaxf(b2v + w20*uu.x + w21*uu.y + w22*uu.z + qp4.x, 0.f);   \
            float c21 = fmaxf(b2v + w20*uu.y + w21*uu.z + w22*uu.w + qp4.y, 0.f);   \
            float c22 = fmaxf(b2v + w20*uu.z + w21*uu.w + w22*nx   + qp4.z, 0.f);   \
            float c23 = fmaxf(b2v + w20*uu.w + w21*nx   + w22*ny   + qp4.w, 0.f);   \
            if (j == 31) { c12 = 0.f; c13 = 0.f; c22 = 0.f; c23 = 0.f; }            \
            uint2 v1; v1.x = packbf2(c10, c11); v1.y = packbf2(c12, c13);           \
            uint2 v2; v2.x = packbf2(c20, c21); v2.y = packbf2(c22, c23);           \
            *(uint2*)&X2[XB][r][2*j]      = v1;                                     \
            *(uint2*)&X2[XB][r][64 + 2*j] = v2;                                     \
        }                                                                           \
    }

    auto gemm = [&](int xb, int psl) {
        float4v acc00 = {0.f,0.f,0.f,0.f}, acc01 = {0.f,0.f,0.f,0.f};
        float4v acc10 = {0.f,0.f,0.f,0.f}, acc11 = {0.f,0.f,0.f,0.f};
        const char* Xb = (const char*)&X2[xb][0][0];
        #pragma unroll
        for (int kt = 0; kt < 8; ++kt) {
            const short8v aa0 = *(const short8v*)(Xb + (mbase + li)*528      + kt*64 + g*16);
            const short8v aa1 = *(const short8v*)(Xb + (mbase + 16 + li)*528 + kt*64 + g*16);
            acc00 = __builtin_amdgcn_mfma_f32_16x16x32_bf16(aa0, bfr0[kt], acc00, 0, 0, 0);
            acc01 = __builtin_amdgcn_mfma_f32_16x16x32_bf16(aa0, bfr1[kt], acc01, 0, 0, 0);
            acc10 = __builtin_amdgcn_mfma_f32_16x16x32_bf16(aa1, bfr0[kt], acc10, 0, 0, 0);
            acc11 = __builtin_amdgcn_mfma_f32_16x16x32_bf16(aa1, bfr1[kt], acc11, 0, 0, 0);
        }
        #pragma unroll
        for (int mi = 0; mi < 2; ++mi) {
            #pragma unroll
            for (int reg = 0; reg < 4; ++reg) {
                const float a0v = mi ? acc10[reg] : acc00[reg];
                const float a1v = mi ? acc11[reg] : acc01[reg];
                float v = wf0 * fmaxf(a0v + qt0, 0.f) + wf1 * fmaxf(a1v + qt1, 0.f);
                v += __shfl_xor(v, 1, 64);
                v += __shfl_xor(v, 2, 64);
                v += __shfl_xor(v, 4, 64);
                v += __shfl_xor(v, 8, 64);
                if (li == 0) pscore[psl][nhalf][mbase + mi*16 + g*4 + reg] = v;
            }
        }
    };

    float val = 0.f;
    auto sig = [&](int psl, int m) {
        if (w == 0) {
            const float d = pscore[psl][0][lane] + pscore[psl][1][lane] + beff - shigh;
            if (m != 0) val += 1.f / (1.f + __expf(-d));
        }
    };

    // ---- pipeline: phase c does gemm(c) || prep(c+1) || load(c+2) || sig(c-1) ----
    PREP_BODY(bufA, 0)
    __syncthreads();                       // X0 ready

    // phase 0
    if (a2) {
        #pragma unroll
        for (int pass = 0; pass < 8; ++pass) {
            const int r = r0 + pass*2 + h;
            bufA[pass] = *(const float4*)(users + (size_t)(base + 128 + r)*ED + 4*j);
        }
    }
    gemm(0, 0);
    if (a1) PREP_BODY(bufB, 1)
    __syncthreads();                       // pscore0(c0), X1 ready

    sig(0, m0);
    if (a1) {
        // phase 1
        if (a3) {
            #pragma unroll
            for (int pass = 0; pass < 8; ++pass) {
                const int r = r0 + pass*2 + h;
                bufB[pass] = *(const float4*)(users + (size_t)(base + 192 + r)*ED + 4*j);
            }
        }
        gemm(1, 1);
        if (a2) PREP_BODY(bufA, 0)
        __syncthreads();                   // pscore1(c1), X0(c2) ready

        sig(1, m1);
        if (a2) {
            // phase 2
            gemm(0, 0);
            if (a3) PREP_BODY(bufB, 1)
            __syncthreads();               // pscore0(c2), X1(c3) ready

            sig(0, m2);
            if (a3) {
                // phase 3
                gemm(1, 1);
                __syncthreads();           // pscore1(c3) ready
                sig(1, m3);
            }
        }
    }

    if (w == 0) {
        #pragma unroll
        for (int off = 32; off > 0; off >>= 1) val += __shfl_xor(val, off, 64);
        if (lane == 0) atomicAdd(out, val);   // device-scope
    }
#undef PREP_BODY
}

extern "C" void kernel_launch(void* const* d_in, const int* in_sizes, int n_in,
                              void* d_out, int out_size, void* d_ws, size_t ws_size,
                              hipStream_t stream)
{
    const float* users    = (const float*)d_in[0];
    const float* top_user = (const float*)d_in[1];
    const float* question = (const float*)d_in[2];
    const int*   uids     = (const int*)d_in[3];
    const float* W1  = (const float*)d_in[4];
    const float* b1  = (const float*)d_in[5];
    const float* W2  = (const float*)d_in[6];
    const float* b2  = (const float*)d_in[7];
    const float* W3  = (const float*)d_in[8];
    const float* b3  = (const float*)d_in[9];
    const float* fw1 = (const float*)d_in[10];
    const float* fb1 = (const float*)d_in[11];
    const float* fw2 = (const float*)d_in[12];
    const float* fb2 = (const float*)d_in[13];
    const float* fw3 = (const float*)d_in[14];
    const float* fb3 = (const float*)d_in[15];
    float* ws  = (float*)d_ws;
    float* out = (float*)d_out;

    hipLaunchKernelGGL(k_prep, dim3(NB + 8), dim3(64), 0, stream,
                       top_user, question, W1, b1, W2, b2, W3, b3,
                       fw1, fb1, fw2, fb2, fw3, fb3, ws, out);
    hipLaunchKernelGGL(k_pairs, dim3(GRID_P), dim3(256), 0, stream,
                       users, uids, ws, out, W1, b1, W2, b2);
}